// Round 7
// baseline (176.193 us; speedup 1.0000x reference)
//
#include <hip/hip_runtime.h>
#include <hip/hip_bf16.h>

#define D_MODEL 1024
#define NUM_HEADS 16
#define D_HEAD 64
#define BATCH 2
#define SEQ 2048
#define TOKENS (BATCH * SEQ) /* 4096 */

typedef __attribute__((ext_vector_type(8))) short bf16x8;
typedef __attribute__((ext_vector_type(4))) float f32x4;
typedef __attribute__((ext_vector_type(2))) unsigned int uint2v;

typedef __attribute__((address_space(1))) const unsigned int as1_uint;
typedef __attribute__((address_space(3))) unsigned int as3_uint;

#define LOG2E 1.44269504088896340736f

// round-to-nearest-even fp32 -> bf16 (bit pattern)
static __device__ __forceinline__ unsigned short f2bf(float f) {
    unsigned int u = __builtin_bit_cast(unsigned int, f);
    u += 0x7fffu + ((u >> 16) & 1u);
    return (unsigned short)(u >> 16);
}

// packed fp32x2 -> bf16x2 (lowers to v_cvt_pk_bf16_f32 on gfx950)
static __device__ __forceinline__ unsigned int pk2bf(float a, float b) {
    __hip_bfloat162 h = __float22bfloat162_rn(float2{a, b});
    unsigned int u;
    __builtin_memcpy(&u, &h, 4);
    return u;
}

// native v_exp_f32 (2^x)
static __device__ __forceinline__ float fast_exp2(float x) {
    return __builtin_amdgcn_exp2f(x);
}

// ---------------------------------------------------------------------------
// One-shot fp32 -> bf16 conversion of x and the 4 weight matrices.
// ---------------------------------------------------------------------------
__global__ __launch_bounds__(256) void convert_bf16(
    const float* __restrict__ x,  const float* __restrict__ Wq,
    const float* __restrict__ Wk, const float* __restrict__ Wv,
    const float* __restrict__ Wp,
    unsigned short* __restrict__ xb,  unsigned short* __restrict__ Wqb,
    unsigned short* __restrict__ Wkb, unsigned short* __restrict__ Wvb,
    unsigned short* __restrict__ Wpb)
{
    int v = blockIdx.x * 256 + threadIdx.x;
    const float* s;
    unsigned short* d;
    int off;
    if (v < (1 << 20)) { s = x; d = xb; off = v; }
    else {
        int u = v - (1 << 20);
        int w = u >> 18;
        off = u & ((1 << 18) - 1);
        s = (w == 0) ? Wq : (w == 1) ? Wk : (w == 2) ? Wv : Wp;
        d = (w == 0) ? Wqb : (w == 1) ? Wkb : (w == 2) ? Wvb : Wpb;
    }
    float4 f = ((const float4*)s)[off];
    ushort4 o = { f2bf(f.x), f2bf(f.y), f2bf(f.z), f2bf(f.w) };
    ((ushort4*)d)[off] = o;
}

// ---------------------------------------------------------------------------
// R21 (proven): FUSED QKV projection, BN=64, 2 blocks/CU, dbuf one-sync.
// ---------------------------------------------------------------------------
__global__ __launch_bounds__(512, 4) void qkv_gemm(
    const unsigned short* __restrict__ xb,
    const unsigned short* __restrict__ Wqb, const unsigned short* __restrict__ Wkb,
    const unsigned short* __restrict__ Wvb,
    unsigned short* __restrict__ Q, unsigned short* __restrict__ Kb,
    unsigned short* __restrict__ Vt)
{
    const int m0 = blockIdx.x * 128;
    const int n0 = blockIdx.y * 64;

    __shared__ __attribute__((aligned(16))) unsigned short sm[40960]; // 80 KB

    const int t = threadIdx.x;
    const int wave = t >> 6, lane = t & 63;
    const int wm = (wave & 1) * 64, wn = (wave >> 1) * 16;
    const int l15 = lane & 15, quad = lane >> 4;
    const int sw = l15 & 7;

    const unsigned short* Wz[3] = { Wqb, Wkb, Wvb };

    f32x4 acc[3][4];
#pragma unroll
    for (int z = 0; z < 3; z++)
#pragma unroll
        for (int i = 0; i < 4; i++) acc[z][i] = (f32x4)0.f;

    // A: 1024 16B chunks (2/thread); each B_z: 512 chunks (1/thread)
    auto stage = [&](int k0, int buf) {
#pragma unroll
        for (int i = 0; i < 2; i++) {
            int fbase = wave * 64 + i * 512;
            int f = fbase + lane;
            int row = f >> 3, cp = f & 7;
            int c = cp ^ (row & 7);
            __builtin_amdgcn_global_load_lds(
                (as1_uint*)&xb[(size_t)(m0 + row) * D_MODEL + k0 + c * 8],
                (as3_uint*)&sm[buf * 20480 + fbase * 8], 16, 0, 0);
        }
        {
            int row = t >> 3, cp = t & 7;
            int c = cp ^ (row & 7);
            int fbase = wave * 64;
#pragma unroll
            for (int z = 0; z < 3; z++)
                __builtin_amdgcn_global_load_lds(
                    (as1_uint*)&Wz[z][(size_t)(n0 + row) * D_MODEL + k0 + c * 8],
                    (as3_uint*)&sm[buf * 20480 + 8192 + z * 4096 + fbase * 8],
                    16, 0, 0);
        }
    };

    stage(0, 0);
    __syncthreads();

    int cur = 0;
    for (int k0 = 0; k0 < D_MODEL; k0 += 64) {
        if (k0 + 64 < D_MODEL) stage(k0 + 64, cur ^ 1);

        const unsigned short* lA = &sm[cur * 20480];
#pragma unroll
        for (int kk = 0; kk < 2; kk++) {
            const int cc = ((kk * 4 + quad) ^ sw) * 8;
            bf16x8 a[4];
#pragma unroll
            for (int mt = 0; mt < 4; mt++)
                a[mt] = *(const bf16x8*)&lA[(wm + mt * 16 + l15) * 64 + cc];
#pragma unroll
            for (int z = 0; z < 3; z++) {
                const unsigned short* lB = &sm[cur * 20480 + 8192 + z * 4096];
                bf16x8 b = *(const bf16x8*)&lB[(wn + l15) * 64 + cc];
#pragma unroll
                for (int mt = 0; mt < 4; mt++)
                    acc[z][mt] = __builtin_amdgcn_mfma_f32_16x16x32_bf16(
                        a[mt], b, acc[z][mt], 0, 0, 0);
            }
        }
        __syncthreads();   // implicit vmcnt(0): next tile landed; cur free
        cur ^= 1;
    }

    // ---- epilogue: Q (scaled by log2e), K, Vt ([b][h][dh][s])
#pragma unroll
    for (int mt = 0; mt < 4; mt++)
#pragma unroll
        for (int r = 0; r < 4; r++) {
            int row = m0 + wm + mt * 16 + quad * 4 + r;
            int col = n0 + wn + l15;
            Q[(size_t)row * D_MODEL + col]  = f2bf(acc[0][mt][r] * LOG2E);
            Kb[(size_t)row * D_MODEL + col] = f2bf(acc[1][mt][r]);
        }
    {
        const int b = m0 >> 11;
        const int srow = (m0 & 2047) + wm + quad * 4;
        const int h = n0 >> 6;
        const int dh = wn + l15;
#pragma unroll
        for (int mt = 0; mt < 4; mt++) {
            ushort4 pk = { f2bf(acc[2][mt][0]), f2bf(acc[2][mt][1]),
                           f2bf(acc[2][mt][2]), f2bf(acc[2][mt][3]) };
            *(ushort4*)&Vt[(size_t)((b * 16 + h) * 64 + dh) * SEQ + srow + mt * 16] = pk;
        }
    }
}

// ---------------------------------------------------------------------------
// Flash attention R22: KVBLK=128. Two 64-key sub-tiles staged per barrier
// pair (each kept in the proven 64x64 XOR-swizzled sub-layout), then TWO
// full compute sub-iterations -- barriers per key halved (32 -> 17/block),
// 2x compute (72 MFMA + 64 exp2) per stage window amortizes the drain and
// covers HBM prefetch latency. 64 KB LDS -> still 2 blocks/CU.
// P in-register via cvt_pk + permlane{32,16}_swap (R18, 0 conflicts).
// Block = (b,h, 128 q), 8 waves = 4 q-strips x 2 s-halves; 32 q/wave.
// LDS layout (shorts): K[sh][u] @ sh*8192 + u*4096;
//                      V[sh][u] @ 16384 + sh*8192 + u*4096.
// ---------------------------------------------------------------------------
__global__ __launch_bounds__(512, 4) void attn(
    const unsigned short* __restrict__ Q, const unsigned short* __restrict__ K,
    const unsigned short* __restrict__ Vt, unsigned short* __restrict__ O)
{
    const int q0 = blockIdx.x * 128;
    const int bh = blockIdx.y;
    const int b = bh >> 4, h = bh & 15;
    const size_t base = (size_t)b * SEQ * D_MODEL + (size_t)h * D_HEAD;
    const size_t baseV = (size_t)bh * D_HEAD * SEQ;

    __shared__ __attribute__((aligned(16))) char smem[65536];
    unsigned short* lds = (unsigned short*)smem;

    const int t = threadIdx.x;
    const int wave = t >> 6, lane = t & 63;
    const int l15 = lane & 15, quad = lane >> 4;
    const int wq = wave & 3;
    const int sh = wave >> 2;
    const int qw = q0 + wq * 32;
    const int sbase = sh * (SEQ / 2);

    unsigned short* lKsh = lds + sh * 4096;            // + u*... see below
    unsigned short* lVsh = lds + 16384 + sh * 4096;
    // NOTE: sub-tile u of shard sh lives at lKsh + sh*4096 ... simpler:
    // K(sh,u) = lds + sh*8192 + u*4096 ; V(sh,u) = lds + 16384 + sh*8192 + u*4096
    unsigned short* lK0 = lds + sh * 8192;
    unsigned short* lV0 = lds + 16384 + sh * 8192;
    (void)lKsh; (void)lVsh;

    bf16x8 ones;
#pragma unroll
    for (int i = 0; i < 8; i++) ones[i] = (short)0x3F80;

    bf16x8 bq[2][2];
#pragma unroll
    for (int mq = 0; mq < 2; mq++)
#pragma unroll
        for (int kk = 0; kk < 2; kk++)
            bq[mq][kk] = *(const bf16x8*)&Q[base +
                (size_t)(qw + mq * 16 + l15) * D_MODEL + kk * 32 + quad * 8];

    const int tl = t & 255;
    const int r0 = tl >> 3, c0 = tl & 7;
    const int cs = (c0 ^ (r0 & 7)) * 8;
    const unsigned short* gK0 = &K[base + (size_t)(sbase + r0) * D_MODEL + c0 * 8];
    const unsigned short* gK1 = &K[base + (size_t)(sbase + r0 + 32) * D_MODEL + c0 * 8];
    const unsigned short* gV0 = &Vt[baseV + (size_t)r0 * SEQ + sbase + c0 * 8];
    const unsigned short* gV1 = &Vt[baseV + (size_t)(r0 + 32) * SEQ + sbase + c0 * 8];

    const int sw = l15 & 7;

    f32x4 o_acc[2][4];
#pragma unroll
    for (int i = 0; i < 2; i++)
#pragma unroll
        for (int j = 0; j < 4; j++) o_acc[i][j] = (f32x4)0.f;
    f32x4 o_l[2];
#pragma unroll
    for (int i = 0; i < 2; i++) o_l[i] = (f32x4)0.f;

    // prefetch round 0 (keys 0..127 of this shard)
    uint4 rKa0 = *(const uint4*)(gK0);
    uint4 rKa1 = *(const uint4*)(gK1);
    uint4 rKb0 = *(const uint4*)(gK0 + (size_t)64 * D_MODEL);
    uint4 rKb1 = *(const uint4*)(gK1 + (size_t)64 * D_MODEL);
    uint4 rVa0 = *(const uint4*)(gV0);
    uint4 rVa1 = *(const uint4*)(gV1);
    uint4 rVb0 = *(const uint4*)(gV0 + 64);
    uint4 rVb1 = *(const uint4*)(gV1 + 64);

    for (int s0 = 0; s0 < SEQ / 2; s0 += 128) {
        __syncthreads();
        *(uint4*)&lK0[r0 * 64 + cs]               = rKa0;
        *(uint4*)&lK0[(r0 + 32) * 64 + cs]        = rKa1;
        *(uint4*)&lK0[4096 + r0 * 64 + cs]        = rKb0;
        *(uint4*)&lK0[4096 + (r0 + 32) * 64 + cs] = rKb1;
        *(uint4*)&lV0[r0 * 64 + cs]               = rVa0;
        *(uint4*)&lV0[(r0 + 32) * 64 + cs]        = rVa1;
        *(uint4*)&lV0[4096 + r0 * 64 + cs]        = rVb0;
        *(uint4*)&lV0[4096 + (r0 + 32) * 64 + cs] = rVb1;
        __syncthreads();

        int sn = (s0 + 128 < SEQ / 2) ? s0 + 128 : 0;
        rKa0 = *(const uint4*)(gK0 + (size_t)sn * D_MODEL);
        rKa1 = *(const uint4*)(gK1 + (size_t)sn * D_MODEL);
        rKb0 = *(const uint4*)(gK0 + (size_t)(sn + 64) * D_MODEL);
        rKb1 = *(const uint4*)(gK1 + (size_t)(sn + 64) * D_MODEL);
        rVa0 = *(const uint4*)(gV0 + sn);
        rVa1 = *(const uint4*)(gV1 + sn);
        rVb0 = *(const uint4*)(gV0 + sn + 64);
        rVb1 = *(const uint4*)(gV1 + sn + 64);

#pragma unroll
        for (int u = 0; u < 2; u++) {
            const unsigned short* lK  = lK0 + u * 4096;
            const unsigned short* lVt = lV0 + u * 4096;

            f32x4 st[4][2];
#pragma unroll
            for (int mt = 0; mt < 4; mt++)
#pragma unroll
                for (int mq = 0; mq < 2; mq++) st[mt][mq] = (f32x4)0.f;
#pragma unroll
            for (int kk = 0; kk < 2; kk++) {
                const int cc = ((kk * 4 + quad) ^ sw) * 8;
#pragma unroll
                for (int mt = 0; mt < 4; mt++) {
                    bf16x8 ak = *(const bf16x8*)&lK[(mt * 16 + l15) * 64 + cc];
#pragma unroll
                    for (int mq = 0; mq < 2; mq++)
                        st[mt][mq] = __builtin_amdgcn_mfma_f32_16x16x32_bf16(
                            ak, bq[mq][kk], st[mt][mq], 0, 0, 0);
                }
            }

#pragma unroll
            for (int mq = 0; mq < 2; mq++)
#pragma unroll
                for (int mt = 0; mt < 4; mt++)
#pragma unroll
                    for (int r = 0; r < 4; r++)
                        st[mt][mq][r] = fast_exp2(st[mt][mq][r]);

            // P in-register: cvt_pk + permlane swaps -> PV A-fragments
            bf16x8 pa[2][2];
#pragma unroll
            for (int mq = 0; mq < 2; mq++)
#pragma unroll
                for (int kk = 0; kk < 2; kk++) {
                    unsigned int cw[4];
#pragma unroll
                    for (int j = 0; j < 2; j++) {
                        unsigned int w0 = pk2bf(st[2 * kk][mq][2 * j],
                                                st[2 * kk][mq][2 * j + 1]);
                        unsigned int w1 = pk2bf(st[2 * kk + 1][mq][2 * j],
                                                st[2 * kk + 1][mq][2 * j + 1]);
                        uint2v uv = __builtin_amdgcn_permlane32_swap(w0, w1, false, false);
                        uint2v f  = __builtin_amdgcn_permlane16_swap(uv[0], uv[1], false, false);
                        cw[j]     = f[0];
                        cw[2 + j] = f[1];
                    }
                    union { unsigned int w[4]; bf16x8 v; } uu;
                    uu.w[0] = cw[0]; uu.w[1] = cw[1]; uu.w[2] = cw[2]; uu.w[3] = cw[3];
                    pa[mq][kk] = uu.v;
                }

#pragma unroll
            for (int kk = 0; kk < 2; kk++) {
                const int cc = ((kk * 4 + quad) ^ sw) * 8;
                bf16x8 bv[4];
#pragma unroll
                for (int nt = 0; nt < 4; nt++)
                    bv[nt] = *(const bf16x8*)&lVt[(nt * 16 + l15) * 64 + cc];
#pragma unroll
                for (int mq = 0; mq < 2; mq++) {
#pragma unroll
                    for (int nt = 0; nt < 4; nt++)
                        o_acc[mq][nt] = __builtin_amdgcn_mfma_f32_16x16x32_bf16(
                            pa[mq][kk], bv[nt], o_acc[mq][nt], 0, 0, 0);
                    o_l[mq] = __builtin_amdgcn_mfma_f32_16x16x32_bf16(
                        pa[mq][kk], ones, o_l[mq], 0, 0, 0);
                }
            }
        }
    }

    float* sO = (float*)&smem[0];
    float* sL = (float*)&smem[36864];
    __syncthreads();
    if (sh == 1) {
#pragma unroll
        for (int mq = 0; mq < 2; mq++) {
#pragma unroll
            for (int r = 0; r < 4; r++)
                sL[wq * 32 + mq * 16 + quad * 4 + r] = o_l[mq][r];
#pragma unroll
            for (int nt = 0; nt < 4; nt++)
#pragma unroll
                for (int r = 0; r < 4; r++)
                    sO[(wq * 32 + mq * 16 + quad * 4 + r) * 68 + nt * 16 + l15] =
                        o_acc[mq][nt][r];
        }
    }
    __syncthreads();
    if (sh == 0) {
#pragma unroll
        for (int mq = 0; mq < 2; mq++) {
            float inv[4];
#pragma unroll
            for (int r = 0; r < 4; r++)
                inv[r] = 1.f / (o_l[mq][r] + sL[wq * 32 + mq * 16 + quad * 4 + r]);
#pragma unroll
            for (int nt = 0; nt < 4; nt++)
#pragma unroll
                for (int r = 0; r < 4; r++) {
                    int row = qw + mq * 16 + quad * 4 + r;
                    float v = o_acc[mq][nt][r] +
                              sO[(wq * 32 + mq * 16 + quad * 4 + r) * 68 + nt * 16 + l15];
                    O[base + (size_t)row * D_MODEL + nt * 16 + l15] = f2bf(v * inv[r]);
                }
        }
    }
}

// ---------------------------------------------------------------------------
// R21 (proven): Output projection, BN=64 + dbuf one-sync, 2 blocks/CU.
// ---------------------------------------------------------------------------
__global__ __launch_bounds__(512, 4) void proj_gemm(
    const unsigned short* __restrict__ A, const unsigned short* __restrict__ W,
    const float* __restrict__ bias, float* __restrict__ out)
{
    const int m0 = blockIdx.x * 128;
    const int n0 = blockIdx.y * 64;

    __shared__ __attribute__((aligned(16))) unsigned short sm[24576]; // 48 KB

    const int t = threadIdx.x;
    const int wave = t >> 6, lane = t & 63;
    const int wm = (wave & 1) * 64, wn = (wave >> 1) * 16;
    const int l15 = lane & 15, quad = lane >> 4;
    const int sw = l15 & 7;

    f32x4 acc[4];
#pragma unroll
    for (int i = 0; i < 4; i++) acc[i] = (f32x4)0.f;

    auto stage = [&](int k0, int buf) {
#pragma unroll
        for (int i = 0; i < 2; i++) {
            int fbase = wave * 64 + i * 512;
            int f = fbase + lane;
            int row = f >> 3, cp = f & 7;
            int c = cp ^ (row & 7);
            __builtin_amdgcn_global_load_lds(
                (as1_uint*)&A[(size_t)(m0 + row) * D_MODEL + k0 + c * 8],
                (as3_uint*)&sm[buf * 12288 + fbase * 8], 16, 0, 0);
        }
        {
            int row = t >> 3, cp = t & 7;
            int c = cp ^ (row & 7);
            int fbase = wave * 64;
            __builtin_amdgcn_global_load_lds(
                (as1_uint*)&W[(size_t)(n0 + row) * D_MODEL + k0 + c * 8],
                (as3_uint*)&sm[buf * 12288 + 8192 + fbase * 8], 16, 0, 0);
        }
    };

    stage(0, 0);
    __syncthreads();

    int cur = 0;
    for (int k0 = 0; k0 < D_MODEL; k0 += 64) {
        if (k0 + 64 < D_MODEL) stage(k0 + 64, cur ^ 1);

        const unsigned short* lA = &sm[cur * 12288];
        const unsigned short* lB = &sm[cur * 12288 + 8192];
#pragma unroll
        for (int kk = 0; kk < 2; kk++) {
            const int cc = ((kk * 4 + quad) ^ sw) * 8;
            bf16x8 a[4];
#pragma unroll
            for (int mt = 0; mt < 4; mt++)
                a[mt] = *(const bf16x8*)&lA[(wm + mt * 16 + l15) * 64 + cc];
            bf16x8 b = *(const bf16x8*)&lB[(wn + l15) * 64 + cc];
#pragma unroll
            for (int mt = 0; mt < 4; mt++)
                acc[mt] = __builtin_amdgcn_mfma_f32_16x16x32_bf16(
                    a[mt], b, acc[mt], 0, 0, 0);
        }
        __syncthreads();
        cur ^= 1;
    }

    const int col = n0 + wn + l15;
    const float bc = bias[col];
#pragma unroll
    for (int mt = 0; mt < 4; mt++)
#pragma unroll
        for (int r = 0; r < 4; r++) {
            int row = m0 + wm + mt * 16 + quad * 4 + r;
            out[(size_t)row * D_MODEL + col] = acc[mt][r] + bc;
        }
}

extern "C" void kernel_launch(void* const* d_in, const int* in_sizes, int n_in,
                              void* d_out, int out_size, void* d_ws, size_t ws_size,
                              hipStream_t stream)
{
    const float* x  = (const float*)d_in[0];
    const float* Wq = (const float*)d_in[2];
    const float* Wk = (const float*)d_in[3];
    const float* Wv = (const float*)d_in[4];
    const float* Wp = (const float*)d_in[5];
    const float* bp = (const float*)d_in[6];
    float* out = (float*)d_out;

    unsigned short* Q   = (unsigned short*)d_ws;
    unsigned short* K   = Q   + (size_t)TOKENS * D_MODEL;
    unsigned short* Vt  = K   + (size_t)TOKENS * D_MODEL;
    unsigned short* O   = Vt  + (size_t)TOKENS * D_MODEL;
    unsigned short* xb  = O   + (size_t)TOKENS * D_MODEL;
    unsigned short* Wqb = xb  + (size_t)TOKENS * D_MODEL;
    unsigned short* Wkb = Wqb + (size_t)D_MODEL * D_MODEL;
    unsigned short* Wvb = Wkb + (size_t)D_MODEL * D_MODEL;
    unsigned short* Wpb = Wvb + (size_t)D_MODEL * D_MODEL;

    convert_bf16<<<8192, 256, 0, stream>>>(x, Wq, Wk, Wv, Wp,
                                           xb, Wqb, Wkb, Wvb, Wpb);
    qkv_gemm<<<dim3(TOKENS / 128, D_MODEL / 64), 512, 0, stream>>>(
        xb, Wqb, Wkb, Wvb, Q, K, Vt);
    attn<<<dim3(SEQ / 128, BATCH * NUM_HEADS), 512, 0, stream>>>(Q, K, Vt, O);
    proj_gemm<<<dim3(TOKENS / 128, D_MODEL / 64), 512, 0, stream>>>(O, Wpb, bp, out);
}

// Round 9
// 172.185 us; speedup vs baseline: 1.0233x; 1.0233x over previous
//
#include <hip/hip_runtime.h>
#include <hip/hip_bf16.h>

#define D_MODEL 1024
#define NUM_HEADS 16
#define D_HEAD 64
#define BATCH 2
#define SEQ 2048
#define TOKENS (BATCH * SEQ) /* 4096 */

typedef __attribute__((ext_vector_type(8))) short bf16x8;
typedef __attribute__((ext_vector_type(4))) float f32x4;
typedef __attribute__((ext_vector_type(2))) unsigned int uint2v;

typedef __attribute__((address_space(1))) const unsigned int as1_uint;
typedef __attribute__((address_space(3))) unsigned int as3_uint;

#define LOG2E 1.44269504088896340736f

// round-to-nearest-even fp32 -> bf16 (bit pattern)
static __device__ __forceinline__ unsigned short f2bf(float f) {
    unsigned int u = __builtin_bit_cast(unsigned int, f);
    u += 0x7fffu + ((u >> 16) & 1u);
    return (unsigned short)(u >> 16);
}

// packed fp32x2 -> bf16x2 (lowers to v_cvt_pk_bf16_f32 on gfx950)
static __device__ __forceinline__ unsigned int pk2bf(float a, float b) {
    __hip_bfloat162 h = __float22bfloat162_rn(float2{a, b});
    unsigned int u;
    __builtin_memcpy(&u, &h, 4);
    return u;
}

// native v_exp_f32 (2^x)
static __device__ __forceinline__ float fast_exp2(float x) {
    return __builtin_amdgcn_exp2f(x);
}

// ---------------------------------------------------------------------------
// One-shot fp32 -> bf16 conversion of x and the 4 weight matrices.
// ---------------------------------------------------------------------------
__global__ __launch_bounds__(256) void convert_bf16(
    const float* __restrict__ x,  const float* __restrict__ Wq,
    const float* __restrict__ Wk, const float* __restrict__ Wv,
    const float* __restrict__ Wp,
    unsigned short* __restrict__ xb,  unsigned short* __restrict__ Wqb,
    unsigned short* __restrict__ Wkb, unsigned short* __restrict__ Wvb,
    unsigned short* __restrict__ Wpb)
{
    int v = blockIdx.x * 256 + threadIdx.x;
    const float* s;
    unsigned short* d;
    int off;
    if (v < (1 << 20)) { s = x; d = xb; off = v; }
    else {
        int u = v - (1 << 20);
        int w = u >> 18;
        off = u & ((1 << 18) - 1);
        s = (w == 0) ? Wq : (w == 1) ? Wk : (w == 2) ? Wv : Wp;
        d = (w == 0) ? Wqb : (w == 1) ? Wkb : (w == 2) ? Wvb : Wpb;
    }
    float4 f = ((const float4*)s)[off];
    ushort4 o = { f2bf(f.x), f2bf(f.y), f2bf(f.z), f2bf(f.w) };
    ((ushort4*)d)[off] = o;
}

// ---------------------------------------------------------------------------
// R21 (proven): FUSED QKV projection, BN=64, 2 blocks/CU, dbuf one-sync.
// ---------------------------------------------------------------------------
__global__ __launch_bounds__(512, 4) void qkv_gemm(
    const unsigned short* __restrict__ xb,
    const unsigned short* __restrict__ Wqb, const unsigned short* __restrict__ Wkb,
    const unsigned short* __restrict__ Wvb,
    unsigned short* __restrict__ Q, unsigned short* __restrict__ Kb,
    unsigned short* __restrict__ Vt)
{
    const int m0 = blockIdx.x * 128;
    const int n0 = blockIdx.y * 64;

    __shared__ __attribute__((aligned(16))) unsigned short sm[40960]; // 80 KB

    const int t = threadIdx.x;
    const int wave = t >> 6, lane = t & 63;
    const int wm = (wave & 1) * 64, wn = (wave >> 1) * 16;
    const int l15 = lane & 15, quad = lane >> 4;
    const int sw = l15 & 7;

    const unsigned short* Wz[3] = { Wqb, Wkb, Wvb };

    f32x4 acc[3][4];
#pragma unroll
    for (int z = 0; z < 3; z++)
#pragma unroll
        for (int i = 0; i < 4; i++) acc[z][i] = (f32x4)0.f;

    // A: 1024 16B chunks (2/thread); each B_z: 512 chunks (1/thread)
    auto stage = [&](int k0, int buf) {
#pragma unroll
        for (int i = 0; i < 2; i++) {
            int fbase = wave * 64 + i * 512;
            int f = fbase + lane;
            int row = f >> 3, cp = f & 7;
            int c = cp ^ (row & 7);
            __builtin_amdgcn_global_load_lds(
                (as1_uint*)&xb[(size_t)(m0 + row) * D_MODEL + k0 + c * 8],
                (as3_uint*)&sm[buf * 20480 + fbase * 8], 16, 0, 0);
        }
        {
            int row = t >> 3, cp = t & 7;
            int c = cp ^ (row & 7);
            int fbase = wave * 64;
#pragma unroll
            for (int z = 0; z < 3; z++)
                __builtin_amdgcn_global_load_lds(
                    (as1_uint*)&Wz[z][(size_t)(n0 + row) * D_MODEL + k0 + c * 8],
                    (as3_uint*)&sm[buf * 20480 + 8192 + z * 4096 + fbase * 8],
                    16, 0, 0);
        }
    };

    stage(0, 0);
    __syncthreads();

    int cur = 0;
    for (int k0 = 0; k0 < D_MODEL; k0 += 64) {
        if (k0 + 64 < D_MODEL) stage(k0 + 64, cur ^ 1);

        const unsigned short* lA = &sm[cur * 20480];
#pragma unroll
        for (int kk = 0; kk < 2; kk++) {
            const int cc = ((kk * 4 + quad) ^ sw) * 8;
            bf16x8 a[4];
#pragma unroll
            for (int mt = 0; mt < 4; mt++)
                a[mt] = *(const bf16x8*)&lA[(wm + mt * 16 + l15) * 64 + cc];
#pragma unroll
            for (int z = 0; z < 3; z++) {
                const unsigned short* lB = &sm[cur * 20480 + 8192 + z * 4096];
                bf16x8 b = *(const bf16x8*)&lB[(wn + l15) * 64 + cc];
#pragma unroll
                for (int mt = 0; mt < 4; mt++)
                    acc[z][mt] = __builtin_amdgcn_mfma_f32_16x16x32_bf16(
                        a[mt], b, acc[z][mt], 0, 0, 0);
            }
        }
        __syncthreads();   // implicit vmcnt(0): next tile landed; cur free
        cur ^= 1;
    }

    // ---- epilogue: Q (scaled by log2e), K, Vt ([b][h][dh][s])
#pragma unroll
    for (int mt = 0; mt < 4; mt++)
#pragma unroll
        for (int r = 0; r < 4; r++) {
            int row = m0 + wm + mt * 16 + quad * 4 + r;
            int col = n0 + wn + l15;
            Q[(size_t)row * D_MODEL + col]  = f2bf(acc[0][mt][r] * LOG2E);
            Kb[(size_t)row * D_MODEL + col] = f2bf(acc[1][mt][r]);
        }
    {
        const int b = m0 >> 11;
        const int srow = (m0 & 2047) + wm + quad * 4;
        const int h = n0 >> 6;
        const int dh = wn + l15;
#pragma unroll
        for (int mt = 0; mt < 4; mt++) {
            ushort4 pk = { f2bf(acc[2][mt][0]), f2bf(acc[2][mt][1]),
                           f2bf(acc[2][mt][2]), f2bf(acc[2][mt][3]) };
            *(ushort4*)&Vt[(size_t)((b * 16 + h) * 64 + dh) * SEQ + srow + mt * 16] = pk;
        }
    }
}

// ---------------------------------------------------------------------------
// Flash attention R23: staging via global_load_lds (pre-swizzled SOURCE,
// linear LDS dest -- same involution as R18: LDS[row][slot] =
// global[row][slot^(row&7)]), LDS double-buffered, ONE barrier per 64-key
// iter (qkv-proven async pattern: issue t+1 loads, compute t, sync drains
// vmcnt). Zero staging VGPRs -- fixes R22's scratch-spill regression.
// KVBLK=64; 64 KB LDS -> 2 blocks/CU. P in-register via cvt_pk +
// permlane{32,16}_swap (0 conflicts). 8 waves = 4 q-strips x 2 s-halves.
// LDS (shorts): K[buf][sh] @ buf*16384 + sh*4096;
//               V[buf][sh] @ 8192 + buf*16384 + sh*4096.
// ---------------------------------------------------------------------------
__global__ __launch_bounds__(512, 4) void attn(
    const unsigned short* __restrict__ Q, const unsigned short* __restrict__ K,
    const unsigned short* __restrict__ Vt, unsigned short* __restrict__ O)
{
    const int q0 = blockIdx.x * 128;
    const int bh = blockIdx.y;
    const int b = bh >> 4, h = bh & 15;
    const size_t base = (size_t)b * SEQ * D_MODEL + (size_t)h * D_HEAD;
    const size_t baseV = (size_t)bh * D_HEAD * SEQ;

    __shared__ __attribute__((aligned(16))) char smem[65536];
    unsigned short* lds = (unsigned short*)smem;

    const int t = threadIdx.x;
    const int wave = t >> 6, lane = t & 63;
    const int l15 = lane & 15, quad = lane >> 4;
    const int wq = wave & 3;
    const int sh = wave >> 2;
    const int qw = q0 + wq * 32;
    const int sbase = sh * (SEQ / 2);

    bf16x8 ones;
#pragma unroll
    for (int i = 0; i < 8; i++) ones[i] = (short)0x3F80;

    bf16x8 bq[2][2];
#pragma unroll
    for (int mq = 0; mq < 2; mq++)
#pragma unroll
        for (int kk = 0; kk < 2; kk++)
            bq[mq][kk] = *(const bf16x8*)&Q[base +
                (size_t)(qw + mq * 16 + l15) * D_MODEL + kk * 32 + quad * 8];

    const int tl = t & 255;
    const int sw = l15 & 7;

    // async staging: chunk f covers LDS bytes f*16 (linear dest); the XOR
    // swizzle is applied to the per-lane GLOBAL source column.
    auto stage = [&](int soff, int buf) {
#pragma unroll
        for (int i = 0; i < 2; i++) {
            int f = tl + i * 256;
            int row = f >> 3;
            int c = (f & 7) ^ (row & 7);
            __builtin_amdgcn_global_load_lds(
                (as1_uint*)&K[base + (size_t)(sbase + soff + row) * D_MODEL + c * 8],
                (as3_uint*)&lds[buf * 16384 + sh * 4096 + f * 8], 16, 0, 0);
            __builtin_amdgcn_global_load_lds(
                (as1_uint*)&Vt[baseV + (size_t)row * SEQ + sbase + soff + c * 8],
                (as3_uint*)&lds[8192 + buf * 16384 + sh * 4096 + f * 8], 16, 0, 0);
        }
    };

    f32x4 o_acc[2][4];
#pragma unroll
    for (int i = 0; i < 2; i++)
#pragma unroll
        for (int j = 0; j < 4; j++) o_acc[i][j] = (f32x4)0.f;
    f32x4 o_l[2];
#pragma unroll
    for (int i = 0; i < 2; i++) o_l[i] = (f32x4)0.f;

    stage(0, 0);
    __syncthreads();

    int cur = 0;
    for (int s0 = 0; s0 < SEQ / 2; s0 += 64) {
        if (s0 + 64 < SEQ / 2) stage(s0 + 64, cur ^ 1);

        const unsigned short* lK  = lds + cur * 16384 + sh * 4096;
        const unsigned short* lVt = lds + 8192 + cur * 16384 + sh * 4096;

        f32x4 st[4][2];
#pragma unroll
        for (int mt = 0; mt < 4; mt++)
#pragma unroll
            for (int mq = 0; mq < 2; mq++) st[mt][mq] = (f32x4)0.f;
#pragma unroll
        for (int kk = 0; kk < 2; kk++) {
            const int cc = ((kk * 4 + quad) ^ sw) * 8;
#pragma unroll
            for (int mt = 0; mt < 4; mt++) {
                bf16x8 ak = *(const bf16x8*)&lK[(mt * 16 + l15) * 64 + cc];
#pragma unroll
                for (int mq = 0; mq < 2; mq++)
                    st[mt][mq] = __builtin_amdgcn_mfma_f32_16x16x32_bf16(
                        ak, bq[mq][kk], st[mt][mq], 0, 0, 0);
            }
        }

#pragma unroll
        for (int mq = 0; mq < 2; mq++)
#pragma unroll
            for (int mt = 0; mt < 4; mt++)
#pragma unroll
                for (int r = 0; r < 4; r++)
                    st[mt][mq][r] = fast_exp2(st[mt][mq][r]);

        // P in-register: cvt_pk + permlane swaps -> PV A-fragments
        bf16x8 pa[2][2];
#pragma unroll
        for (int mq = 0; mq < 2; mq++)
#pragma unroll
            for (int kk = 0; kk < 2; kk++) {
                unsigned int cw[4];
#pragma unroll
                for (int j = 0; j < 2; j++) {
                    unsigned int w0 = pk2bf(st[2 * kk][mq][2 * j],
                                            st[2 * kk][mq][2 * j + 1]);
                    unsigned int w1 = pk2bf(st[2 * kk + 1][mq][2 * j],
                                            st[2 * kk + 1][mq][2 * j + 1]);
                    uint2v uv = __builtin_amdgcn_permlane32_swap(w0, w1, false, false);
                    uint2v f  = __builtin_amdgcn_permlane16_swap(uv[0], uv[1], false, false);
                    cw[j]     = f[0];
                    cw[2 + j] = f[1];
                }
                union { unsigned int w[4]; bf16x8 v; } uu;
                uu.w[0] = cw[0]; uu.w[1] = cw[1]; uu.w[2] = cw[2]; uu.w[3] = cw[3];
                pa[mq][kk] = uu.v;
            }

#pragma unroll
        for (int kk = 0; kk < 2; kk++) {
            const int cc = ((kk * 4 + quad) ^ sw) * 8;
            bf16x8 bv[4];
#pragma unroll
            for (int nt = 0; nt < 4; nt++)
                bv[nt] = *(const bf16x8*)&lVt[(nt * 16 + l15) * 64 + cc];
#pragma unroll
            for (int mq = 0; mq < 2; mq++) {
#pragma unroll
                for (int nt = 0; nt < 4; nt++)
                    o_acc[mq][nt] = __builtin_amdgcn_mfma_f32_16x16x32_bf16(
                        pa[mq][kk], bv[nt], o_acc[mq][nt], 0, 0, 0);
                o_l[mq] = __builtin_amdgcn_mfma_f32_16x16x32_bf16(
                    pa[mq][kk], ones, o_l[mq], 0, 0, 0);
            }
        }
        __syncthreads();   // drains vmcnt: next tile landed; cur free
        cur ^= 1;
    }

    float* sO = (float*)&smem[0];
    float* sL = (float*)&smem[36864];
    if (sh == 1) {
#pragma unroll
        for (int mq = 0; mq < 2; mq++) {
#pragma unroll
            for (int r = 0; r < 4; r++)
                sL[wq * 32 + mq * 16 + quad * 4 + r] = o_l[mq][r];
#pragma unroll
            for (int nt = 0; nt < 4; nt++)
#pragma unroll
                for (int r = 0; r < 4; r++)
                    sO[(wq * 32 + mq * 16 + quad * 4 + r) * 68 + nt * 16 + l15] =
                        o_acc[mq][nt][r];
        }
    }
    __syncthreads();
    if (sh == 0) {
#pragma unroll
        for (int mq = 0; mq < 2; mq++) {
            float inv[4];
#pragma unroll
            for (int r = 0; r < 4; r++)
                inv[r] = 1.f / (o_l[mq][r] + sL[wq * 32 + mq * 16 + quad * 4 + r]);
#pragma unroll
            for (int nt = 0; nt < 4; nt++)
#pragma unroll
                for (int r = 0; r < 4; r++) {
                    int row = qw + mq * 16 + quad * 4 + r;
                    float v = o_acc[mq][nt][r] +
                              sO[(wq * 32 + mq * 16 + quad * 4 + r) * 68 + nt * 16 + l15];
                    O[base + (size_t)row * D_MODEL + nt * 16 + l15] = f2bf(v * inv[r]);
                }
        }
    }
}

// ---------------------------------------------------------------------------
// R21 (proven): Output projection, BN=64 + dbuf one-sync, 2 blocks/CU.
// ---------------------------------------------------------------------------
__global__ __launch_bounds__(512, 4) void proj_gemm(
    const unsigned short* __restrict__ A, const unsigned short* __restrict__ W,
    const float* __restrict__ bias, float* __restrict__ out)
{
    const int m0 = blockIdx.x * 128;
    const int n0 = blockIdx.y * 64;

    __shared__ __attribute__((aligned(16))) unsigned short sm[24576]; // 48 KB

    const int t = threadIdx.x;
    const int wave = t >> 6, lane = t & 63;
    const int wm = (wave & 1) * 64, wn = (wave >> 1) * 16;
    const int l15 = lane & 15, quad = lane >> 4;
    const int sw = l15 & 7;

    f32x4 acc[4];
#pragma unroll
    for (int i = 0; i < 4; i++) acc[i] = (f32x4)0.f;

    auto stage = [&](int k0, int buf) {
#pragma unroll
        for (int i = 0; i < 2; i++) {
            int fbase = wave * 64 + i * 512;
            int f = fbase + lane;
            int row = f >> 3, cp = f & 7;
            int c = cp ^ (row & 7);
            __builtin_amdgcn_global_load_lds(
                (as1_uint*)&A[(size_t)(m0 + row) * D_MODEL + k0 + c * 8],
                (as3_uint*)&sm[buf * 12288 + fbase * 8], 16, 0, 0);
        }
        {
            int row = t >> 3, cp = t & 7;
            int c = cp ^ (row & 7);
            int fbase = wave * 64;
            __builtin_amdgcn_global_load_lds(
                (as1_uint*)&W[(size_t)(n0 + row) * D_MODEL + k0 + c * 8],
                (as3_uint*)&sm[buf * 12288 + 8192 + fbase * 8], 16, 0, 0);
        }
    };

    stage(0, 0);
    __syncthreads();

    int cur = 0;
    for (int k0 = 0; k0 < D_MODEL; k0 += 64) {
        if (k0 + 64 < D_MODEL) stage(k0 + 64, cur ^ 1);

        const unsigned short* lA = &sm[cur * 12288];
        const unsigned short* lB = &sm[cur * 12288 + 8192];
#pragma unroll
        for (int kk = 0; kk < 2; kk++) {
            const int cc = ((kk * 4 + quad) ^ sw) * 8;
            bf16x8 a[4];
#pragma unroll
            for (int mt = 0; mt < 4; mt++)
                a[mt] = *(const bf16x8*)&lA[(wm + mt * 16 + l15) * 64 + cc];
            bf16x8 b = *(const bf16x8*)&lB[(wn + l15) * 64 + cc];
#pragma unroll
            for (int mt = 0; mt < 4; mt++)
                acc[mt] = __builtin_amdgcn_mfma_f32_16x16x32_bf16(
                    a[mt], b, acc[mt], 0, 0, 0);
        }
        __syncthreads();
        cur ^= 1;
    }

    const int col = n0 + wn + l15;
    const float bc = bias[col];
#pragma unroll
    for (int mt = 0; mt < 4; mt++)
#pragma unroll
        for (int r = 0; r < 4; r++) {
            int row = m0 + wm + mt * 16 + quad * 4 + r;
            out[(size_t)row * D_MODEL + col] = acc[mt][r] + bc;
        }
}

extern "C" void kernel_launch(void* const* d_in, const int* in_sizes, int n_in,
                              void* d_out, int out_size, void* d_ws, size_t ws_size,
                              hipStream_t stream)
{
    const float* x  = (const float*)d_in[0];
    const float* Wq = (const float*)d_in[2];
    const float* Wk = (const float*)d_in[3];
    const float* Wv = (const float*)d_in[4];
    const float* Wp = (const float*)d_in[5];
    const float* bp = (const float*)d_in[6];
    float* out = (float*)d_out;

    unsigned short* Q   = (unsigned short*)d_ws;
    unsigned short* K   = Q   + (size_t)TOKENS * D_MODEL;
    unsigned short* Vt  = K   + (size_t)TOKENS * D_MODEL;
    unsigned short* O   = Vt  + (size_t)TOKENS * D_MODEL;
    unsigned short* xb  = O   + (size_t)TOKENS * D_MODEL;
    unsigned short* Wqb = xb  + (size_t)TOKENS * D_MODEL;
    unsigned short* Wkb = Wqb + (size_t)D_MODEL * D_MODEL;
    unsigned short* Wvb = Wkb + (size_t)D_MODEL * D_MODEL;
    unsigned short* Wpb = Wvb + (size_t)D_MODEL * D_MODEL;

    convert_bf16<<<8192, 256, 0, stream>>>(x, Wq, Wk, Wv, Wp,
                                           xb, Wqb, Wkb, Wvb, Wpb);
    qkv_gemm<<<dim3(TOKENS / 128, D_MODEL / 64), 512, 0, stream>>>(
        xb, Wqb, Wkb, Wvb, Q, K, Vt);
    attn<<<dim3(SEQ / 128, BATCH * NUM_HEADS), 512, 0, stream>>>(Q, K, Vt, O);
    proj_gemm<<<dim3(TOKENS / 128, D_MODEL / 64), 512, 0, stream>>>(O, Wpb, bp, out);
}